// Round 4
// baseline (2457.427 us; speedup 1.0000x reference)
//
#include <hip/hip_runtime.h>

#define N 8192
#define DIN 64
#define DOUT 128
#define KNN 16
#define NCHUNK 64
#define CHUNK 128          /* N / NCHUNK */
#define MSAMP 1024         /* presample count per row */
#define PRE_NCHUNK 64
#define PRE_L 16           /* samples per pre-chunk */
#define PRE_STRIDE 8       /* sampled j = 8*s */
#define CAND_C 512         /* candidate buffer capacity per row */
#define ROWS_PRE 16

typedef unsigned long long u64;

__device__ __forceinline__ unsigned mono(float f) {
    unsigned u = __float_as_uint(f);
    return (u & 0x80000000u) ? ~u : (u | 0x80000000u);
}

// K1: sq norms + U = x@(W1a-W1b)+b1, V = x@W1b (16 rows/block)
__global__ __launch_bounds__(256) void k_pre(const float* __restrict__ x,
                                             const float* __restrict__ W1,
                                             const float* __restrict__ b1,
                                             float* __restrict__ sq,
                                             float* __restrict__ U,
                                             float* __restrict__ V) {
    __shared__ float xs[ROWS_PRE][DIN];
    int t = threadIdx.x;
    int r0 = blockIdx.x * ROWS_PRE;
    const float4* x4 = (const float4*)x;
    ((float4*)xs)[t] = x4[(size_t)r0 * (DIN / 4) + t];
    __syncthreads();
    if (t < ROWS_PRE) {
        const float4* xr = (const float4*)xs[t];
        float s0 = 0.f, s1 = 0.f, s2 = 0.f, s3 = 0.f;
#pragma unroll
        for (int q = 0; q < DIN / 4; ++q) {
            float4 a = xr[q];
            s0 = fmaf(a.x, a.x, s0); s1 = fmaf(a.y, a.y, s1);
            s2 = fmaf(a.z, a.z, s2); s3 = fmaf(a.w, a.w, s3);
        }
        sq[r0 + t] = (s0 + s1) + (s2 + s3);
    }
    int o = t & 127, g = t >> 7;
    float aU[8], aV[8];
#pragma unroll
    for (int u = 0; u < 8; ++u) { aU[u] = 0.f; aV[u] = 0.f; }
    for (int kk = 0; kk < DIN; ++kk) {
        float whi = W1[kk * DOUT + o];
        float wlo = W1[(DIN + kk) * DOUT + o];
        float wd = whi - wlo;
#pragma unroll
        for (int u = 0; u < 8; ++u) {
            float xv = xs[g * 8 + u][kk];
            aU[u] = fmaf(xv, wd, aU[u]);
            aV[u] = fmaf(xv, wlo, aV[u]);
        }
    }
    float bb = b1[o];
#pragma unroll
    for (int u = 0; u < 8; ++u) {
        int r = r0 + g * 8 + u;
        U[(size_t)r * DOUT + o] = aU[u] + bb;
        V[(size_t)r * DOUT + o] = aV[u];
    }
}

// K2a: presample — write mono dist-bits of 16 sampled j's per (row, chunk).
// No selection at all: prek[s][row], coalesced across rows.
__global__ __launch_bounds__(256, 8) void k_presample(const float* __restrict__ x,
                                                      const float* __restrict__ sq,
                                                      unsigned* __restrict__ prek) {
    int t = threadIdx.x;
    int c = blockIdx.x;
    int row = blockIdx.y * 256 + t;
    const float4* x4 = (const float4*)x;
    float4 xi[DIN / 4];
#pragma unroll
    for (int q = 0; q < DIN / 4; ++q) xi[q] = x4[(size_t)row * (DIN / 4) + q];
    float sqi = sq[row];

    for (int sl = 0; sl < PRE_L; ++sl) {
        int s = c * PRE_L + sl;
        int j = s * PRE_STRIDE;
        const float4* bj = x4 + (size_t)j * (DIN / 4);   // uniform -> s_load
        float s0 = 0.f, s1 = 0.f, s2 = 0.f, s3 = 0.f;
#pragma unroll
        for (int q = 0; q < DIN / 4; ++q) {
            float4 b = bj[q];
            s0 = fmaf(xi[q].x, b.x, s0); s1 = fmaf(xi[q].y, b.y, s1);
            s2 = fmaf(xi[q].z, b.z, s2); s3 = fmaf(xi[q].w, b.w, s3);
        }
        float d = (s0 + s1) + (s2 + s3);
        float dist = fmaf(-2.0f, d, sqi + sq[j]);
        prek[(size_t)s * N + row] = mono(dist);
    }
}

// K2b: tau[row] = 16th-smallest u32 of the row's 1024 sampled dist-bits
// (= hi32 of the 16th-smallest u64 key: hi32 monotone under u64 order).
// Also zeroes cnt[row]. One wave per row.
__global__ __launch_bounds__(256) void k_tau(const unsigned* __restrict__ prek,
                                             unsigned* __restrict__ tauhi,
                                             int* __restrict__ cnt) {
    int wave = threadIdx.x >> 6, lane = threadIdx.x & 63;
    int row = blockIdx.x * 4 + wave;
    unsigned k[16];
#pragma unroll
    for (int u = 0; u < 16; ++u)
        k[u] = prek[(size_t)(u * 64 + lane) * N + row];
    unsigned m = 0;
#pragma unroll
    for (int t = 0; t < KNN; ++t) {
        m = k[0];
#pragma unroll
        for (int u = 1; u < 16; ++u) m = min(m, k[u]);
#pragma unroll
        for (int off = 32; off >= 1; off >>= 1)
            m = min(m, (unsigned)__shfl_xor((int)m, off, 64));
#pragma unroll
        for (int u = 0; u < 16; ++u)
            if (k[u] == m) k[u] = 0xFFFFFFFFu;   // dup-invalidate: conservative
    }
    if (lane == 0) { tauhi[row] = m; cnt[row] = 0; }
}

// K2c: gated full scan with atomic append. A passer's key goes straight to
// the row's candidate buffer — no in-register list. All true top-16 members
// pass the gate (their key <= true 16th <= sampled 16th = tau).
__global__ __launch_bounds__(256, 8) void k_dist_topk(const float* __restrict__ x,
                                                      const float* __restrict__ sq,
                                                      const unsigned* __restrict__ tauhi,
                                                      int* __restrict__ cnt,
                                                      u64* __restrict__ cand) {
    int t = threadIdx.x;
    int chunk = blockIdx.x;
    int row = blockIdx.y * 256 + t;
    const float4* x4 = (const float4*)x;

    float4 xi[DIN / 4];
#pragma unroll
    for (int q = 0; q < DIN / 4; ++q) xi[q] = x4[(size_t)row * (DIN / 4) + q];
    float sqi = sq[row];
    unsigned th = tauhi[row];

    int j0 = chunk * CHUNK;
#pragma unroll 2
    for (int jj = 0; jj < CHUNK; ++jj) {
        int j = j0 + jj;
        const float4* bj = x4 + (size_t)j * (DIN / 4);   // uniform -> s_load
        float s0 = 0.f, s1 = 0.f, s2 = 0.f, s3 = 0.f;
#pragma unroll
        for (int q = 0; q < DIN / 4; ++q) {
            float4 b = bj[q];
            s0 = fmaf(xi[q].x, b.x, s0); s1 = fmaf(xi[q].y, b.y, s1);
            s2 = fmaf(xi[q].z, b.z, s2); s3 = fmaf(xi[q].w, b.w, s3);
        }
        float d = (s0 + s1) + (s2 + s3);
        float dist = fmaf(-2.0f, d, sqi + sq[j]);
        unsigned mh = mono(dist);
        if (mh <= th) {                                  // rare (~1/64 per lane)
            int slot = atomicAdd(&cnt[row], 1);
            if (slot < CAND_C)
                cand[(size_t)row * CAND_C + slot] = ((u64)mh << 32) | (unsigned)j;
        }
    }
}

// K3: top-16 of the row's candidate buffer -> knn indices. One wave per row.
__global__ __launch_bounds__(256) void k_merge(const int* __restrict__ cnt,
                                               const u64* __restrict__ cand,
                                               int* __restrict__ knn) {
    int wave = threadIdx.x >> 6, lane = threadIdx.x & 63;
    int row = blockIdx.x * 4 + wave;
    int c = cnt[row];
    if (c > CAND_C) c = CAND_C;
    u64 k[CAND_C / 64];
#pragma unroll
    for (int u = 0; u < CAND_C / 64; ++u) {
        int idx = lane + 64 * u;
        k[u] = (idx < c) ? cand[(size_t)row * CAND_C + idx]
                         : 0xFFFFFFFFFFFFFFFFull;
    }
#pragma unroll
    for (int t = 0; t < KNN; ++t) {
        u64 m = k[0];
#pragma unroll
        for (int u = 1; u < CAND_C / 64; ++u) m = (k[u] < m) ? k[u] : m;
#pragma unroll
        for (int off = 32; off >= 1; off >>= 1) {
            u64 o = __shfl_xor(m, off, 64);
            m = (o < m) ? o : m;
        }
        if (lane == t) knn[row * KNN + t] = (int)(unsigned)(m & 0xFFFFFFFFull);
#pragma unroll
        for (int u = 0; u < CAND_C / 64; ++u)
            if (k[u] == m) k[u] = 0xFFFFFFFFFFFFFFFFull;
    }
}

// K4: agg[i] = mean_j relu(U[i]+V[knn[i][j]]);  out = agg@W2 + b2.
__global__ __launch_bounds__(256) void k_aggout(const float* __restrict__ U,
                                                const float* __restrict__ V,
                                                const int* __restrict__ knn,
                                                const float* __restrict__ W2,
                                                const float* __restrict__ b2,
                                                float* __restrict__ out) {
    __shared__ float ag[2][DOUT];
    int t = threadIdx.x;
    int r = t >> 7;
    int o = t & 127;
    int i = blockIdx.x * 2 + r;
    float u = U[(size_t)i * DOUT + o];
    const int* nb = knn + i * KNN;       // wave-uniform
    float acc = 0.f;
#pragma unroll
    for (int q = 0; q < KNN; ++q) {
        int j = nb[q];
        float v = V[(size_t)j * DOUT + o];
        acc += fmaxf(u + v, 0.0f);
    }
    ag[r][o] = acc * (1.0f / KNN);
    __syncthreads();
    float a2 = 0.f;
#pragma unroll 4
    for (int kk = 0; kk < DOUT; ++kk)
        a2 = fmaf(ag[r][kk], W2[kk * DOUT + o], a2);
    out[(size_t)i * DOUT + o] = a2 + b2[o];
}

extern "C" void kernel_launch(void* const* d_in, const int* in_sizes, int n_in,
                              void* d_out, int out_size, void* d_ws, size_t ws_size,
                              hipStream_t stream) {
    const float* x  = (const float*)d_in[0];
    const float* W1 = (const float*)d_in[1];
    const float* b1 = (const float*)d_in[2];
    const float* W2 = (const float*)d_in[3];
    const float* b2 = (const float*)d_in[4];
    float* out = (float*)d_out;

    char* ws = (char*)d_ws;
    float*    sq    = (float*)ws;                       // 32 KB
    unsigned* tauhi = (unsigned*)(ws + 32768);          // 32 KB
    int*      cnt   = (int*)(ws + 65536);               // 32 KB
    float*    U     = (float*)(ws + 98304);             // 4 MB
    float*    V     = U + (size_t)N * DOUT;             // 4 MB
    int*      knn   = (int*)(V + (size_t)N * DOUT);     // 512 KB
    char*     region = (char*)(knn + (size_t)N * KNN);  // 33.5 MB shared:
    unsigned* prek  = (unsigned*)region;                //   prek dead after k_tau
    u64*      cand  = (u64*)region;                     //   cand written after
    // total ws use ~42.6 MB (same as round 3)

    k_pre<<<N / ROWS_PRE, 256, 0, stream>>>(x, W1, b1, sq, U, V);
    k_presample<<<dim3(PRE_NCHUNK, N / 256), 256, 0, stream>>>(x, sq, prek);
    k_tau<<<N / 4, 256, 0, stream>>>(prek, tauhi, cnt);
    k_dist_topk<<<dim3(NCHUNK, N / 256), 256, 0, stream>>>(x, sq, tauhi, cnt, cand);
    k_merge<<<N / 4, 256, 0, stream>>>(cnt, cand, knn);
    k_aggout<<<N / 2, 256, 0, stream>>>(U, V, knn, W2, b2, out);
}

// Round 5
// 282.320 us; speedup vs baseline: 8.7044x; 8.7044x over previous
//
#include <hip/hip_runtime.h>

#define N 8192
#define DIN 64
#define DOUT 128
#define KNN 16
#define MSAMP 1024         /* presample columns (stride 8) */
#define NBX 8              /* j-split in main scan */
#define CAND_R 64          /* slots per (row, bx) region */
#define CAND_C (NBX * CAND_R)   /* 512 per row */
#define EPS 0.1f           /* gate margin >> bf16-split dist error (~2e-3) */
#define ROWS_PRE 16

typedef unsigned long long u64;
typedef __attribute__((ext_vector_type(8))) short bf16x8;
typedef __attribute__((ext_vector_type(4))) float floatx4;

__device__ __forceinline__ unsigned mono(float f) {
    unsigned u = __float_as_uint(f);
    return (u & 0x80000000u) ? ~u : (u | 0x80000000u);
}
__device__ __forceinline__ unsigned short f2bf(float f) {   // RNE float->bf16
    unsigned u = __float_as_uint(f);
    return (unsigned short)((u + 0x7FFFu + ((u >> 16) & 1u)) >> 16);
}
__device__ __forceinline__ float bf2f(unsigned short h) {
    return __uint_as_float((unsigned)h << 16);
}

// K1: sq norms + U = x@(W1a-W1b)+b1, V = x@W1b + bf16 hi/lo split of x.
__global__ __launch_bounds__(256) void k_pre(const float* __restrict__ x,
                                             const float* __restrict__ W1,
                                             const float* __restrict__ b1,
                                             float* __restrict__ sq,
                                             float* __restrict__ U,
                                             float* __restrict__ V,
                                             unsigned short* __restrict__ Xh,
                                             unsigned short* __restrict__ Xl) {
    __shared__ float xs[ROWS_PRE][DIN];
    int t = threadIdx.x;
    int r0 = blockIdx.x * ROWS_PRE;
    const float4* x4 = (const float4*)x;
    float4 xv = x4[(size_t)r0 * (DIN / 4) + t];
    ((float4*)xs)[t] = xv;
    // bf16 split: x = H + L (+ tiny residual)
    ushort4 h4, l4;
    h4.x = f2bf(xv.x); l4.x = f2bf(xv.x - bf2f(h4.x));
    h4.y = f2bf(xv.y); l4.y = f2bf(xv.y - bf2f(h4.y));
    h4.z = f2bf(xv.z); l4.z = f2bf(xv.z - bf2f(h4.z));
    h4.w = f2bf(xv.w); l4.w = f2bf(xv.w - bf2f(h4.w));
    int off = r0 * DIN + t * 4;
    *(ushort4*)&Xh[off] = h4;
    *(ushort4*)&Xl[off] = l4;
    __syncthreads();
    if (t < ROWS_PRE) {
        const float4* xr = (const float4*)xs[t];
        float s0 = 0.f, s1 = 0.f, s2 = 0.f, s3 = 0.f;
#pragma unroll
        for (int q = 0; q < DIN / 4; ++q) {
            float4 a = xr[q];
            s0 = fmaf(a.x, a.x, s0); s1 = fmaf(a.y, a.y, s1);
            s2 = fmaf(a.z, a.z, s2); s3 = fmaf(a.w, a.w, s3);
        }
        sq[r0 + t] = (s0 + s1) + (s2 + s3);
    }
    int o = t & 127, g = t >> 7;
    float aU[8], aV[8];
#pragma unroll
    for (int u = 0; u < 8; ++u) { aU[u] = 0.f; aV[u] = 0.f; }
    for (int kk = 0; kk < DIN; ++kk) {
        float whi = W1[kk * DOUT + o];
        float wlo = W1[(DIN + kk) * DOUT + o];
        float wd = whi - wlo;
#pragma unroll
        for (int u = 0; u < 8; ++u) {
            float xvv = xs[g * 8 + u][kk];
            aU[u] = fmaf(xvv, wd, aU[u]);
            aV[u] = fmaf(xvv, wlo, aV[u]);
        }
    }
    float bb = b1[o];
#pragma unroll
    for (int u = 0; u < 8; ++u) {
        int r = r0 + g * 8 + u;
        U[(size_t)r * DOUT + o] = aU[u] + bb;
        V[(size_t)r * DOUT + o] = aV[u];
    }
}

// K2a: MFMA presample — approx dists to 1024 sampled j (stride 8) per row.
// Wave owns a 16-row tile; 16x16x32 bf16 MFMA, D = HH + HL + LH.
// A/B frag: elem row = lane&15, k = (lane>>4)*8 + e (m89-verified).
// C/D: col = lane&15, row = (lane>>4)*4 + reg (m89/m91-verified).
__global__ __launch_bounds__(256, 4) void k_presample(const unsigned short* __restrict__ Xh,
                                                      const unsigned short* __restrict__ Xl,
                                                      const float* __restrict__ sq,
                                                      float* __restrict__ prek) {
    int tid = threadIdx.x, w = tid >> 6, l = tid & 63;
    int m = l & 15, ko = (l >> 4) * 8;
    int rt = blockIdx.y * 4 + w;
    size_t arow = (size_t)(rt * 16 + m) * DIN;
    bf16x8 aH0 = *(const bf16x8*)(Xh + arow + ko);
    bf16x8 aH1 = *(const bf16x8*)(Xh + arow + 32 + ko);
    bf16x8 aL0 = *(const bf16x8*)(Xl + arow + ko);
    bf16x8 aL1 = *(const bf16x8*)(Xl + arow + 32 + ko);
    int rg[4]; float si[4];
#pragma unroll
    for (int reg = 0; reg < 4; ++reg) {
        rg[reg] = rt * 16 + (l >> 4) * 4 + reg;
        si[reg] = sq[rg[reg]];
    }
    for (int it = 0; it < 16; ++it) {
        int jt = blockIdx.x * 16 + it;
        int scol = jt * 16 + m;
        int j = scol * 8;
        size_t brow = (size_t)j * DIN;
        bf16x8 bH0 = *(const bf16x8*)(Xh + brow + ko);
        bf16x8 bH1 = *(const bf16x8*)(Xh + brow + 32 + ko);
        bf16x8 bL0 = *(const bf16x8*)(Xl + brow + ko);
        bf16x8 bL1 = *(const bf16x8*)(Xl + brow + 32 + ko);
        floatx4 acc = {0.f, 0.f, 0.f, 0.f};
        acc = __builtin_amdgcn_mfma_f32_16x16x32_bf16(aH0, bH0, acc, 0, 0, 0);
        acc = __builtin_amdgcn_mfma_f32_16x16x32_bf16(aH1, bH1, acc, 0, 0, 0);
        acc = __builtin_amdgcn_mfma_f32_16x16x32_bf16(aH0, bL0, acc, 0, 0, 0);
        acc = __builtin_amdgcn_mfma_f32_16x16x32_bf16(aH1, bL1, acc, 0, 0, 0);
        acc = __builtin_amdgcn_mfma_f32_16x16x32_bf16(aL0, bH0, acc, 0, 0, 0);
        acc = __builtin_amdgcn_mfma_f32_16x16x32_bf16(aL1, bH1, acc, 0, 0, 0);
        float sqj = sq[j];
#pragma unroll
        for (int reg = 0; reg < 4; ++reg) {
            float dist = fmaf(-2.0f, acc[reg], si[reg] + sqj);
            prek[(size_t)rg[reg] * MSAMP + scol] = dist;
        }
    }
}

// K2b: tau[row] = 16th-smallest sampled approx dist (upper bound on true
// 16th + error; duplicates invalidated conservatively). One wave per row.
__global__ __launch_bounds__(256, 4) void k_tau(const float* __restrict__ prek,
                                                float* __restrict__ tauf) {
    int w = threadIdx.x >> 6, l = threadIdx.x & 63;
    int row = blockIdx.x * 4 + w;
    float v[16];
#pragma unroll
    for (int u = 0; u < 16; ++u)
        v[u] = prek[(size_t)row * MSAMP + l + 64 * u];
    float m = 0.f;
#pragma unroll
    for (int t = 0; t < KNN; ++t) {
        m = v[0];
#pragma unroll
        for (int u = 1; u < 16; ++u) m = fminf(m, v[u]);
#pragma unroll
        for (int off = 32; off >= 1; off >>= 1)
            m = fminf(m, __shfl_xor(m, off, 64));
#pragma unroll
        for (int u = 0; u < 16; ++u)
            if (v[u] == m) v[u] = 3.0e38f;
    }
    if (l == 0) tauf[row] = m;
}

// K2c: MFMA main scan. Block = 4 waves = 4 row-tiles, common j-tile staged in
// LDS (pad 72 shorts/row -> <=2-way banks). Gate dist<=tau+EPS; passers append
// j to exclusive (row,bx) region via ballot-prefix slots (no atomics).
__global__ __launch_bounds__(256, 4) void k_main(const unsigned short* __restrict__ Xh,
                                                 const unsigned short* __restrict__ Xl,
                                                 const float* __restrict__ sq,
                                                 const float* __restrict__ tauf,
                                                 unsigned* __restrict__ cand,
                                                 unsigned* __restrict__ cntpart) {
    __shared__ __align__(16) short ldsH[16 * 72];
    __shared__ __align__(16) short ldsL[16 * 72];
    int tid = threadIdx.x, w = tid >> 6, l = tid & 63;
    int m = l & 15, ko = (l >> 4) * 8;
    int bx = blockIdx.x;
    int rt = blockIdx.y * 4 + w;
    size_t arow = (size_t)(rt * 16 + m) * DIN;
    bf16x8 aH0 = *(const bf16x8*)(Xh + arow + ko);
    bf16x8 aH1 = *(const bf16x8*)(Xh + arow + 32 + ko);
    bf16x8 aL0 = *(const bf16x8*)(Xl + arow + ko);
    bf16x8 aL1 = *(const bf16x8*)(Xl + arow + 32 + ko);
    int rg[4]; float T[4]; int rowcnt[4];
#pragma unroll
    for (int reg = 0; reg < 4; ++reg) {
        rg[reg] = rt * 16 + (l >> 4) * 4 + reg;
        T[reg] = tauf[rg[reg]] + EPS - sq[rg[reg]];
        rowcnt[reg] = 0;
    }
    int qs = l & 48;                       // quad (16-lane) base in ballot
    unsigned lmask = (1u << (l & 15)) - 1u;
    int sarr = tid >> 7, srw = (tid >> 3) & 15, sk8 = (tid & 7) * 8;
    const unsigned short* sbase = sarr ? Xl : Xh;
    short* sdst = (sarr ? ldsL : ldsH) + srw * 72 + sk8;

    for (int jt = bx * 64; jt < bx * 64 + 64; ++jt) {
        __syncthreads();
        *(bf16x8*)sdst = *(const bf16x8*)(sbase + (size_t)(jt * 16 + srw) * DIN + sk8);
        __syncthreads();
        bf16x8 bH0 = *(const bf16x8*)&ldsH[m * 72 + ko];
        bf16x8 bH1 = *(const bf16x8*)&ldsH[m * 72 + 32 + ko];
        bf16x8 bL0 = *(const bf16x8*)&ldsL[m * 72 + ko];
        bf16x8 bL1 = *(const bf16x8*)&ldsL[m * 72 + 32 + ko];
        floatx4 acc = {0.f, 0.f, 0.f, 0.f};
        acc = __builtin_amdgcn_mfma_f32_16x16x32_bf16(aH0, bH0, acc, 0, 0, 0);
        acc = __builtin_amdgcn_mfma_f32_16x16x32_bf16(aH1, bH1, acc, 0, 0, 0);
        acc = __builtin_amdgcn_mfma_f32_16x16x32_bf16(aH0, bL0, acc, 0, 0, 0);
        acc = __builtin_amdgcn_mfma_f32_16x16x32_bf16(aH1, bL1, acc, 0, 0, 0);
        acc = __builtin_amdgcn_mfma_f32_16x16x32_bf16(aL0, bH0, acc, 0, 0, 0);
        acc = __builtin_amdgcn_mfma_f32_16x16x32_bf16(aL1, bH1, acc, 0, 0, 0);
        int jcol = jt * 16 + m;
        float sqj = sq[jcol];
#pragma unroll
        for (int reg = 0; reg < 4; ++reg) {
            float tv = fmaf(-2.0f, acc[reg], sqj);   // dist - si <= tau+EPS-si
            bool pass = tv <= T[reg];
            u64 bal = __ballot(pass);
            unsigned m16 = (unsigned)((bal >> qs) & 0xFFFFull);
            if (pass) {
                int slot = rowcnt[reg] + __popc(m16 & lmask);
                if (slot < CAND_R)
                    cand[(size_t)rg[reg] * CAND_C + bx * CAND_R + slot] = (unsigned)jcol;
            }
            rowcnt[reg] += __popc(m16);
        }
    }
    if ((l & 15) == 0) {
#pragma unroll
        for (int reg = 0; reg < 4; ++reg)
            cntpart[rg[reg] * NBX + bx] = (unsigned)min(rowcnt[reg], CAND_R);
    }
}

// K3: exact fp32 re-verify of survivors + top-16 select. One wave per row.
__global__ __launch_bounds__(256, 2) void k_exact(const float* __restrict__ x,
                                                  const float* __restrict__ sq,
                                                  const unsigned* __restrict__ cntpart,
                                                  const unsigned* __restrict__ cand,
                                                  int* __restrict__ knn) {
    __shared__ unsigned lds[4][CAND_C];
    int w = threadIdx.x >> 6, l = threadIdx.x & 63;
    int row = blockIdx.x * 4 + w;
    const float4* x4 = (const float4*)x;
    float4 xi[DIN / 4];
#pragma unroll
    for (int q = 0; q < DIN / 4; ++q) xi[q] = x4[(size_t)row * (DIN / 4) + q];
    float sqi = sq[row];
    int base = 0;
#pragma unroll
    for (int bxx = 0; bxx < NBX; ++bxx) {
        int c = (int)cntpart[row * NBX + bxx];
        c = min(c, CAND_R);
        if (l < c) lds[w][base + l] = cand[(size_t)row * CAND_C + bxx * CAND_R + l];
        base += c;
    }
    __syncthreads();
    u64 keys[8];
#pragma unroll
    for (int u = 0; u < 8; ++u) {
        int idx = l + 64 * u;
        u64 kk = 0xFFFFFFFFFFFFFFFFull;
        if (idx < base) {
            int j = (int)lds[w][idx];
            const float4* bj = x4 + (size_t)j * (DIN / 4);
            float s0 = 0.f, s1 = 0.f, s2 = 0.f, s3 = 0.f;
#pragma unroll
            for (int q = 0; q < DIN / 4; ++q) {
                float4 b = bj[q];
                s0 = fmaf(xi[q].x, b.x, s0); s1 = fmaf(xi[q].y, b.y, s1);
                s2 = fmaf(xi[q].z, b.z, s2); s3 = fmaf(xi[q].w, b.w, s3);
            }
            float d = (s0 + s1) + (s2 + s3);
            float dist = fmaf(-2.0f, d, sqi + sq[j]);
            kk = ((u64)mono(dist) << 32) | (unsigned)j;
        }
        keys[u] = kk;
    }
#pragma unroll
    for (int t = 0; t < KNN; ++t) {
        u64 mm = keys[0];
#pragma unroll
        for (int u = 1; u < 8; ++u) mm = (keys[u] < mm) ? keys[u] : mm;
#pragma unroll
        for (int off = 32; off >= 1; off >>= 1) {
            u64 o = __shfl_xor(mm, off, 64);
            mm = (o < mm) ? o : mm;
        }
        if (l == t) knn[row * KNN + t] = (int)(unsigned)(mm & 0xFFFFFFFFull);
#pragma unroll
        for (int u = 0; u < 8; ++u)
            if (keys[u] == mm) keys[u] = 0xFFFFFFFFFFFFFFFFull;
    }
}

// K4: agg[i] = mean_j relu(U[i]+V[knn[i][j]]);  out = agg@W2 + b2.
__global__ __launch_bounds__(256) void k_aggout(const float* __restrict__ U,
                                                const float* __restrict__ V,
                                                const int* __restrict__ knn,
                                                const float* __restrict__ W2,
                                                const float* __restrict__ b2,
                                                float* __restrict__ out) {
    __shared__ float ag[2][DOUT];
    int t = threadIdx.x;
    int r = t >> 7;
    int o = t & 127;
    int i = blockIdx.x * 2 + r;
    float u = U[(size_t)i * DOUT + o];
    const int* nb = knn + i * KNN;
    float acc = 0.f;
#pragma unroll
    for (int q = 0; q < KNN; ++q) {
        int j = nb[q];
        float v = V[(size_t)j * DOUT + o];
        acc += fmaxf(u + v, 0.0f);
    }
    ag[r][o] = acc * (1.0f / KNN);
    __syncthreads();
    float a2 = 0.f;
#pragma unroll 4
    for (int kk = 0; kk < DOUT; ++kk)
        a2 = fmaf(ag[r][kk], W2[kk * DOUT + o], a2);
    out[(size_t)i * DOUT + o] = a2 + b2[o];
}

extern "C" void kernel_launch(void* const* d_in, const int* in_sizes, int n_in,
                              void* d_out, int out_size, void* d_ws, size_t ws_size,
                              hipStream_t stream) {
    const float* x  = (const float*)d_in[0];
    const float* W1 = (const float*)d_in[1];
    const float* b1 = (const float*)d_in[2];
    const float* W2 = (const float*)d_in[3];
    const float* b2 = (const float*)d_in[4];
    float* out = (float*)d_out;

    char* ws = (char*)d_ws;
    float*          sq      = (float*)(ws);                      // 32 KB
    float*          tauf    = (float*)(ws + 32768);              // 32 KB
    float*          U       = (float*)(ws + 65536);              // 4 MB
    float*          V       = (float*)(ws + 65536 + 4194304);    // 4 MB
    int*            knn     = (int*)(ws + 65536 + 8388608);      // 512 KB
    unsigned short* Xh      = (unsigned short*)(ws + 8978432);   // 1 MB
    unsigned short* Xl      = (unsigned short*)(ws + 10027008);  // 1 MB
    unsigned*       cntpart = (unsigned*)(ws + 11075584);        // 256 KB
    char*           region  = ws + 11337728;                     // 32 MB shared
    float*          prek    = (float*)region;   // dead after k_tau
    unsigned*       cand    = (unsigned*)region;// written after k_tau
    // total ws use ~42.8 MB (same envelope as round 4)

    k_pre<<<N / ROWS_PRE, 256, 0, stream>>>(x, W1, b1, sq, U, V, Xh, Xl);
    k_presample<<<dim3(4, 128), 256, 0, stream>>>(Xh, Xl, sq, prek);
    k_tau<<<N / 4, 256, 0, stream>>>(prek, tauf);
    k_main<<<dim3(NBX, 128), 256, 0, stream>>>(Xh, Xl, sq, tauf, cand, cntpart);
    k_exact<<<N / 4, 256, 0, stream>>>(x, sq, cntpart, cand, knn);
    k_aggout<<<N / 2, 256, 0, stream>>>(U, V, knn, W2, b2, out);
}

// Round 7
// 277.127 us; speedup vs baseline: 8.8675x; 1.0187x over previous
//
#include <hip/hip_runtime.h>

#define N 8192
#define DIN 64
#define DOUT 128
#define KNN 16
#define MSAMP 1024         /* presample columns (stride 8) */
#define NBX 8              /* j-split in main scan */
#define CAND_R 80          /* slots per (row, bx) region */
#define CAND_C (NBX * CAND_R)   /* 640 per row */
#define EPS 2.5f           /* >= 2x worst-case HH-only dist error (~0.9) */
#define ROWS_PRE 16

typedef unsigned long long u64;
typedef __attribute__((ext_vector_type(8))) short bf16x8;
typedef __attribute__((ext_vector_type(4))) float floatx4;

__device__ __forceinline__ unsigned mono(float f) {
    unsigned u = __float_as_uint(f);
    return (u & 0x80000000u) ? ~u : (u | 0x80000000u);
}
__device__ __forceinline__ unsigned short f2bf(float f) {   // RNE float->bf16
    unsigned u = __float_as_uint(f);
    return (unsigned short)((u + 0x7FFFu + ((u >> 16) & 1u)) >> 16);
}

// K1: sq norms + U = x@(W1a-W1b)+b1, V = x@W1b + bf16 cast of x.
__global__ __launch_bounds__(256) void k_pre(const float* __restrict__ x,
                                             const float* __restrict__ W1,
                                             const float* __restrict__ b1,
                                             float* __restrict__ sq,
                                             float* __restrict__ U,
                                             float* __restrict__ V,
                                             unsigned short* __restrict__ Xh) {
    __shared__ float xs[ROWS_PRE][DIN];
    int t = threadIdx.x;
    int r0 = blockIdx.x * ROWS_PRE;
    const float4* x4 = (const float4*)x;
    float4 xv = x4[(size_t)r0 * (DIN / 4) + t];
    ((float4*)xs)[t] = xv;
    ushort4 h4;
    h4.x = f2bf(xv.x); h4.y = f2bf(xv.y);
    h4.z = f2bf(xv.z); h4.w = f2bf(xv.w);
    *(ushort4*)&Xh[r0 * DIN + t * 4] = h4;
    __syncthreads();
    if (t < ROWS_PRE) {
        const float4* xr = (const float4*)xs[t];
        float s0 = 0.f, s1 = 0.f, s2 = 0.f, s3 = 0.f;
#pragma unroll
        for (int q = 0; q < DIN / 4; ++q) {
            float4 a = xr[q];
            s0 = fmaf(a.x, a.x, s0); s1 = fmaf(a.y, a.y, s1);
            s2 = fmaf(a.z, a.z, s2); s3 = fmaf(a.w, a.w, s3);
        }
        sq[r0 + t] = (s0 + s1) + (s2 + s3);
    }
    int o = t & 127, g = t >> 7;
    float aU[8], aV[8];
#pragma unroll
    for (int u = 0; u < 8; ++u) { aU[u] = 0.f; aV[u] = 0.f; }
    for (int kk = 0; kk < DIN; ++kk) {
        float whi = W1[kk * DOUT + o];
        float wlo = W1[(DIN + kk) * DOUT + o];
        float wd = whi - wlo;
#pragma unroll
        for (int u = 0; u < 8; ++u) {
            float xvv = xs[g * 8 + u][kk];
            aU[u] = fmaf(xvv, wd, aU[u]);
            aV[u] = fmaf(xvv, wlo, aV[u]);
        }
    }
    float bb = b1[o];
#pragma unroll
    for (int u = 0; u < 8; ++u) {
        int r = r0 + g * 8 + u;
        U[(size_t)r * DOUT + o] = aU[u] + bb;
        V[(size_t)r * DOUT + o] = aV[u];
    }
}

// K2a: MFMA presample (HH only) — approx dists to 1024 sampled j (stride 8),
// quantized u16 round-UP (q/128 >= approx dist, conservative for tau).
__global__ __launch_bounds__(256, 4) void k_presample(const unsigned short* __restrict__ Xh,
                                                      const float* __restrict__ sq,
                                                      unsigned short* __restrict__ prekq) {
    int tid = threadIdx.x, w = tid >> 6, l = tid & 63;
    int m = l & 15, ko = (l >> 4) * 8;
    int rt = blockIdx.y * 4 + w;
    size_t arow = (size_t)(rt * 16 + m) * DIN;
    bf16x8 aH0 = *(const bf16x8*)(Xh + arow + ko);
    bf16x8 aH1 = *(const bf16x8*)(Xh + arow + 32 + ko);
    int rg[4]; float si[4];
#pragma unroll
    for (int reg = 0; reg < 4; ++reg) {
        rg[reg] = rt * 16 + (l >> 4) * 4 + reg;
        si[reg] = sq[rg[reg]];
    }
    for (int it = 0; it < 16; ++it) {
        int jt = blockIdx.x * 16 + it;
        int scol = jt * 16 + m;
        int j = scol * 8;
        size_t brow = (size_t)j * DIN;
        bf16x8 bH0 = *(const bf16x8*)(Xh + brow + ko);
        bf16x8 bH1 = *(const bf16x8*)(Xh + brow + 32 + ko);
        floatx4 acc = {0.f, 0.f, 0.f, 0.f};
        acc = __builtin_amdgcn_mfma_f32_16x16x32_bf16(aH0, bH0, acc, 0, 0, 0);
        acc = __builtin_amdgcn_mfma_f32_16x16x32_bf16(aH1, bH1, acc, 0, 0, 0);
        float sqj = sq[j];
#pragma unroll
        for (int reg = 0; reg < 4; ++reg) {
            float dist = fmaf(-2.0f, acc[reg], si[reg] + sqj);
            int q = (int)(dist * 128.0f) + 2;           // >= ceil(dist*128)
            q = max(q, 0); q = min(q, 65535);
            prekq[(size_t)rg[reg] * MSAMP + scol] = (unsigned short)q;
        }
    }
}

// K2b: tau[row] = 16th-smallest sampled quantized dist / 128 (round-up quant
// + duplicate-kill both enlarge tau -> conservative). One wave per row.
__global__ __launch_bounds__(256, 4) void k_tau(const unsigned short* __restrict__ prekq,
                                                float* __restrict__ tauf) {
    int w = threadIdx.x >> 6, l = threadIdx.x & 63;
    int row = blockIdx.x * 4 + w;
    unsigned v[16];
#pragma unroll
    for (int u = 0; u < 16; ++u)
        v[u] = prekq[(size_t)row * MSAMP + l + 64 * u];
    unsigned m = 0;
#pragma unroll
    for (int t = 0; t < KNN; ++t) {
        m = v[0];
#pragma unroll
        for (int u = 1; u < 16; ++u) m = min(m, v[u]);
#pragma unroll
        for (int off = 32; off >= 1; off >>= 1)
            m = min(m, (unsigned)__shfl_xor((int)m, off, 64));
#pragma unroll
        for (int u = 0; u < 16; ++u)
            if (v[u] == m) v[u] = 0xFFFFFFFFu;
    }
    if (l == 0) tauf[row] = (float)m * (1.0f / 128.0f);
}

// K2c: MFMA main scan (HH only). Block = 4 waves = 4 row-tiles; 64 j-rows
// staged in LDS per barrier round. Gate dist<=tau+EPS; passers append u16
// jcol to exclusive (row,bx) region via ballot-prefix slots.
__global__ __launch_bounds__(256, 4) void k_main(const unsigned short* __restrict__ Xh,
                                                 const float* __restrict__ sq,
                                                 const float* __restrict__ tauf,
                                                 unsigned short* __restrict__ cand,
                                                 unsigned* __restrict__ cntpart) {
    __shared__ __align__(16) short ldsH[64 * 72];
    int tid = threadIdx.x, w = tid >> 6, l = tid & 63;
    int m = l & 15, ko = (l >> 4) * 8;
    int bx = blockIdx.x;
    int rt = blockIdx.y * 4 + w;
    size_t arow = (size_t)(rt * 16 + m) * DIN;
    bf16x8 aH0 = *(const bf16x8*)(Xh + arow + ko);
    bf16x8 aH1 = *(const bf16x8*)(Xh + arow + 32 + ko);
    int rg[4]; float T[4]; int rowcnt[4];
#pragma unroll
    for (int reg = 0; reg < 4; ++reg) {
        rg[reg] = rt * 16 + (l >> 4) * 4 + reg;
        T[reg] = tauf[rg[reg]] + EPS - sq[rg[reg]];
        rowcnt[reg] = 0;
    }
    int qs = l & 48;
    unsigned lmask = (1u << (l & 15)) - 1u;
    int srw = tid >> 3, scol8 = (tid & 7) * 8;

    for (int st = 0; st < 16; ++st) {
        int jbase = bx * 1024 + st * 64;
        __syncthreads();
        *(bf16x8*)&ldsH[srw * 72 + scol8] =
            *(const bf16x8*)(Xh + (size_t)(jbase + srw) * DIN + scol8);
        *(bf16x8*)&ldsH[(srw + 32) * 72 + scol8] =
            *(const bf16x8*)(Xh + (size_t)(jbase + srw + 32) * DIN + scol8);
        __syncthreads();
#pragma unroll
        for (int it = 0; it < 4; ++it) {
            int br = it * 16 + m;
            bf16x8 bH0 = *(const bf16x8*)&ldsH[br * 72 + ko];
            bf16x8 bH1 = *(const bf16x8*)&ldsH[br * 72 + 32 + ko];
            floatx4 acc = {0.f, 0.f, 0.f, 0.f};
            acc = __builtin_amdgcn_mfma_f32_16x16x32_bf16(aH0, bH0, acc, 0, 0, 0);
            acc = __builtin_amdgcn_mfma_f32_16x16x32_bf16(aH1, bH1, acc, 0, 0, 0);
            int jcol = jbase + it * 16 + m;
            float sqj = sq[jcol];
#pragma unroll
            for (int reg = 0; reg < 4; ++reg) {
                float tv = fmaf(-2.0f, acc[reg], sqj);   // dist - si
                bool pass = tv <= T[reg];
                u64 bal = __ballot(pass);
                unsigned m16 = (unsigned)((bal >> qs) & 0xFFFFull);
                if (pass) {
                    int slot = rowcnt[reg] + __popc(m16 & lmask);
                    if (slot < CAND_R)
                        cand[(size_t)rg[reg] * CAND_C + bx * CAND_R + slot] =
                            (unsigned short)jcol;
                }
                rowcnt[reg] += __popc(m16);
            }
        }
    }
    if ((l & 15) == 0) {
#pragma unroll
        for (int reg = 0; reg < 4; ++reg)
            cntpart[rg[reg] * NBX + bx] = (unsigned)min(rowcnt[reg], CAND_R);
    }
}

// K3: exact fp32 re-verify + top-16. One wave per row. Candidate rows staged
// coalesced into LDS (batch 32, pad 65 -> conflict-free), then each lane
// computes its candidate's dot in the EXACT striped order of rounds 1-5
// (bit-identical distances -> selection identical to the passing rounds).
__global__ __launch_bounds__(256) void k_exact(const float* __restrict__ x,
                                               const float* __restrict__ sq,
                                               const unsigned* __restrict__ cntpart,
                                               const unsigned short* __restrict__ cand,
                                               int* __restrict__ knn) {
    __shared__ float rowsb[4][32][65];        // 33280 B
    __shared__ float xs[4][DIN];              //  1024 B
    __shared__ unsigned short cj[4][CAND_C];  //  5120 B
    __shared__ u64 keys[4][CAND_C];           // 20480 B  (total ~59.9 KB)
    int w = threadIdx.x >> 6, l = threadIdx.x & 63;
    int row = blockIdx.x * 4 + w;
    // per-wave LDS slices only -> no cross-wave barriers needed
    xs[w][l] = x[(size_t)row * DIN + l];
    int base = 0;
#pragma unroll
    for (int bxx = 0; bxx < NBX; ++bxx) {
        int c = (int)cntpart[row * NBX + bxx];
        c = min(c, CAND_R);
        for (int s = l; s < c; s += 64)
            cj[w][base + s] = cand[(size_t)row * CAND_C + bxx * CAND_R + s];
        base += c;
    }
    float sqi = sq[row];
    int nb = (base + 31) >> 5;
    for (int b = 0; b < nb; ++b) {
        int c0 = b * 32;
        int nc = min(32, base - c0);
        for (int c = 0; c < nc; ++c) {               // coalesced stage
            int j = (int)cj[w][c0 + c];              // LDS broadcast
            rowsb[w][c][l] = x[(size_t)j * DIN + l];
        }
        if (l < nc) {
            const float* rr = rowsb[w][l];
            float s0 = 0.f, s1 = 0.f, s2 = 0.f, s3 = 0.f;
#pragma unroll
            for (int q = 0; q < DIN / 4; ++q) {      // striped order == r1-r5
                s0 = fmaf(xs[w][4 * q + 0], rr[4 * q + 0], s0);
                s1 = fmaf(xs[w][4 * q + 1], rr[4 * q + 1], s1);
                s2 = fmaf(xs[w][4 * q + 2], rr[4 * q + 2], s2);
                s3 = fmaf(xs[w][4 * q + 3], rr[4 * q + 3], s3);
            }
            float d = (s0 + s1) + (s2 + s3);
            int j = (int)cj[w][c0 + l];
            float dist = fmaf(-2.0f, d, sqi + sq[j]);
            keys[w][c0 + l] = ((u64)mono(dist) << 32) | (unsigned)j;
        }
    }
    u64 kk[CAND_C / 64];
#pragma unroll
    for (int u = 0; u < CAND_C / 64; ++u) {
        int idx = l + 64 * u;
        kk[u] = (idx < base) ? keys[w][idx] : 0xFFFFFFFFFFFFFFFFull;
    }
#pragma unroll
    for (int t = 0; t < KNN; ++t) {
        u64 mm = kk[0];
#pragma unroll
        for (int u = 1; u < CAND_C / 64; ++u) mm = (kk[u] < mm) ? kk[u] : mm;
#pragma unroll
        for (int off = 32; off >= 1; off >>= 1) {
            u64 o = __shfl_xor(mm, off, 64);
            mm = (o < mm) ? o : mm;
        }
        if (l == t) knn[row * KNN + t] = (int)(unsigned)(mm & 0xFFFFFFFFull);
#pragma unroll
        for (int u = 0; u < CAND_C / 64; ++u)
            if (kk[u] == mm) kk[u] = 0xFFFFFFFFFFFFFFFFull;
    }
}

// K4: agg[i] = mean_j relu(U[i]+V[knn[i][j]]);  out = agg@W2 + b2.
__global__ __launch_bounds__(256) void k_aggout(const float* __restrict__ U,
                                                const float* __restrict__ V,
                                                const int* __restrict__ knn,
                                                const float* __restrict__ W2,
                                                const float* __restrict__ b2,
                                                float* __restrict__ out) {
    __shared__ float ag[2][DOUT];
    int t = threadIdx.x;
    int r = t >> 7;
    int o = t & 127;
    int i = blockIdx.x * 2 + r;
    float u = U[(size_t)i * DOUT + o];
    const int* nb = knn + i * KNN;
    float acc = 0.f;
#pragma unroll
    for (int q = 0; q < KNN; ++q) {
        int j = nb[q];
        float v = V[(size_t)j * DOUT + o];
        acc += fmaxf(u + v, 0.0f);
    }
    ag[r][o] = acc * (1.0f / KNN);
    __syncthreads();
    float a2 = 0.f;
#pragma unroll 4
    for (int kk = 0; kk < DOUT; ++kk)
        a2 = fmaf(ag[r][kk], W2[kk * DOUT + o], a2);
    out[(size_t)i * DOUT + o] = a2 + b2[o];
}

extern "C" void kernel_launch(void* const* d_in, const int* in_sizes, int n_in,
                              void* d_out, int out_size, void* d_ws, size_t ws_size,
                              hipStream_t stream) {
    const float* x  = (const float*)d_in[0];
    const float* W1 = (const float*)d_in[1];
    const float* b1 = (const float*)d_in[2];
    const float* W2 = (const float*)d_in[3];
    const float* b2 = (const float*)d_in[4];
    float* out = (float*)d_out;

    char* ws = (char*)d_ws;
    float*          sq      = (float*)(ws);                      // 32 KB
    float*          tauf    = (float*)(ws + 32768);              // 32 KB
    float*          U       = (float*)(ws + 65536);              // 4 MB
    float*          V       = (float*)(ws + 4259840);            // 4 MB
    int*            knn     = (int*)(ws + 8454144);              // 512 KB
    unsigned short* Xh      = (unsigned short*)(ws + 8978432);   // 1 MB
    unsigned*       cntpart = (unsigned*)(ws + 10027008);        // 256 KB
    char*           region  = ws + 10289152;                     // 16.8 MB shared:
    unsigned short* prekq   = (unsigned short*)region;           //  dead after k_tau
    unsigned short* cand    = (unsigned short*)region;           //  written after
    // total ws use ~27.1 MB

    k_pre<<<N / ROWS_PRE, 256, 0, stream>>>(x, W1, b1, sq, U, V, Xh);
    k_presample<<<dim3(4, 128), 256, 0, stream>>>(Xh, sq, prekq);
    k_tau<<<N / 4, 256, 0, stream>>>(prekq, tauf);
    k_main<<<dim3(NBX, 128), 256, 0, stream>>>(Xh, sq, tauf, cand, cntpart);
    k_exact<<<N / 4, 256, 0, stream>>>(x, sq, cntpart, cand, knn);
    k_aggout<<<N / 2, 256, 0, stream>>>(U, V, knn, W2, b2, out);
}

// Round 8
// 242.707 us; speedup vs baseline: 10.1251x; 1.1418x over previous
//
#include <hip/hip_runtime.h>

#define N 8192
#define DIN 64
#define DOUT 128
#define KNN 16
#define MSAMP 1024         /* presample columns (stride 8) */
#define NBX 8              /* j-split in main scan */
#define CAND_R 80          /* slots per (row, bx) region */
#define CAND_C (NBX * CAND_R)   /* 640 per row */
#define EPS 2.5f           /* >= 2x worst-case HH-only dist error (~0.9) */
#define ROWS_PRE 16

typedef unsigned long long u64;
typedef __attribute__((ext_vector_type(8))) short bf16x8;
typedef __attribute__((ext_vector_type(4))) float floatx4;

__device__ __forceinline__ unsigned mono(float f) {
    unsigned u = __float_as_uint(f);
    return (u & 0x80000000u) ? ~u : (u | 0x80000000u);
}
__device__ __forceinline__ unsigned short f2bf(float f) {   // RNE float->bf16
    unsigned u = __float_as_uint(f);
    return (unsigned short)((u + 0x7FFFu + ((u >> 16) & 1u)) >> 16);
}

// K1: sq norms + U = x@(W1a-W1b)+b1, V = x@W1b + bf16 cast of x.
__global__ __launch_bounds__(256) void k_pre(const float* __restrict__ x,
                                             const float* __restrict__ W1,
                                             const float* __restrict__ b1,
                                             float* __restrict__ sq,
                                             float* __restrict__ U,
                                             float* __restrict__ V,
                                             unsigned short* __restrict__ Xh) {
    __shared__ float xs[ROWS_PRE][DIN];
    int t = threadIdx.x;
    int r0 = blockIdx.x * ROWS_PRE;
    const float4* x4 = (const float4*)x;
    float4 xv = x4[(size_t)r0 * (DIN / 4) + t];
    ((float4*)xs)[t] = xv;
    ushort4 h4;
    h4.x = f2bf(xv.x); h4.y = f2bf(xv.y);
    h4.z = f2bf(xv.z); h4.w = f2bf(xv.w);
    *(ushort4*)&Xh[r0 * DIN + t * 4] = h4;
    __syncthreads();
    if (t < ROWS_PRE) {
        const float4* xr = (const float4*)xs[t];
        float s0 = 0.f, s1 = 0.f, s2 = 0.f, s3 = 0.f;
#pragma unroll
        for (int q = 0; q < DIN / 4; ++q) {
            float4 a = xr[q];
            s0 = fmaf(a.x, a.x, s0); s1 = fmaf(a.y, a.y, s1);
            s2 = fmaf(a.z, a.z, s2); s3 = fmaf(a.w, a.w, s3);
        }
        sq[r0 + t] = (s0 + s1) + (s2 + s3);
    }
    int o = t & 127, g = t >> 7;
    float aU[8], aV[8];
#pragma unroll
    for (int u = 0; u < 8; ++u) { aU[u] = 0.f; aV[u] = 0.f; }
    for (int kk = 0; kk < DIN; ++kk) {
        float whi = W1[kk * DOUT + o];
        float wlo = W1[(DIN + kk) * DOUT + o];
        float wd = whi - wlo;
#pragma unroll
        for (int u = 0; u < 8; ++u) {
            float xvv = xs[g * 8 + u][kk];
            aU[u] = fmaf(xvv, wd, aU[u]);
            aV[u] = fmaf(xvv, wlo, aV[u]);
        }
    }
    float bb = b1[o];
#pragma unroll
    for (int u = 0; u < 8; ++u) {
        int r = r0 + g * 8 + u;
        U[(size_t)r * DOUT + o] = aU[u] + bb;
        V[(size_t)r * DOUT + o] = aV[u];
    }
}

// K2a: MFMA presample (HH only) — approx dists to 1024 sampled j (stride 8),
// quantized u16 round-UP (q/128 >= approx dist, conservative for tau).
__global__ __launch_bounds__(256, 4) void k_presample(const unsigned short* __restrict__ Xh,
                                                      const float* __restrict__ sq,
                                                      unsigned short* __restrict__ prekq) {
    int tid = threadIdx.x, w = tid >> 6, l = tid & 63;
    int m = l & 15, ko = (l >> 4) * 8;
    int rt = blockIdx.y * 4 + w;
    size_t arow = (size_t)(rt * 16 + m) * DIN;
    bf16x8 aH0 = *(const bf16x8*)(Xh + arow + ko);
    bf16x8 aH1 = *(const bf16x8*)(Xh + arow + 32 + ko);
    int rg[4]; float si[4];
#pragma unroll
    for (int reg = 0; reg < 4; ++reg) {
        rg[reg] = rt * 16 + (l >> 4) * 4 + reg;
        si[reg] = sq[rg[reg]];
    }
    for (int it = 0; it < 16; ++it) {
        int jt = blockIdx.x * 16 + it;
        int scol = jt * 16 + m;
        int j = scol * 8;
        size_t brow = (size_t)j * DIN;
        bf16x8 bH0 = *(const bf16x8*)(Xh + brow + ko);
        bf16x8 bH1 = *(const bf16x8*)(Xh + brow + 32 + ko);
        floatx4 acc = {0.f, 0.f, 0.f, 0.f};
        acc = __builtin_amdgcn_mfma_f32_16x16x32_bf16(aH0, bH0, acc, 0, 0, 0);
        acc = __builtin_amdgcn_mfma_f32_16x16x32_bf16(aH1, bH1, acc, 0, 0, 0);
        float sqj = sq[j];
#pragma unroll
        for (int reg = 0; reg < 4; ++reg) {
            float dist = fmaf(-2.0f, acc[reg], si[reg] + sqj);
            int q = (int)(dist * 128.0f) + 2;           // >= ceil(dist*128)
            q = max(q, 0); q = min(q, 65535);
            prekq[(size_t)rg[reg] * MSAMP + scol] = (unsigned short)q;
        }
    }
}

// K2b: tau[row] = 16th-smallest sampled quantized dist / 128 (round-up quant
// + duplicate-kill both enlarge tau -> conservative). One wave per row.
__global__ __launch_bounds__(256, 4) void k_tau(const unsigned short* __restrict__ prekq,
                                                float* __restrict__ tauf) {
    int w = threadIdx.x >> 6, l = threadIdx.x & 63;
    int row = blockIdx.x * 4 + w;
    unsigned v[16];
#pragma unroll
    for (int u = 0; u < 16; ++u)
        v[u] = prekq[(size_t)row * MSAMP + l + 64 * u];
    unsigned m = 0;
#pragma unroll
    for (int t = 0; t < KNN; ++t) {
        m = v[0];
#pragma unroll
        for (int u = 1; u < 16; ++u) m = min(m, v[u]);
#pragma unroll
        for (int off = 32; off >= 1; off >>= 1)
            m = min(m, (unsigned)__shfl_xor((int)m, off, 64));
#pragma unroll
        for (int u = 0; u < 16; ++u)
            if (v[u] == m) v[u] = 0xFFFFFFFFu;
    }
    if (l == 0) tauf[row] = (float)m * (1.0f / 128.0f);
}

// K2c: MFMA main scan (HH only). Block = 4 waves = 4 row-tiles; 64 j-rows
// staged in LDS per barrier round. Gate dist<=tau+EPS; passers append u16
// jcol to exclusive (row,bx) region via ballot-prefix slots.
__global__ __launch_bounds__(256, 4) void k_main(const unsigned short* __restrict__ Xh,
                                                 const float* __restrict__ sq,
                                                 const float* __restrict__ tauf,
                                                 unsigned short* __restrict__ cand,
                                                 unsigned* __restrict__ cntpart) {
    __shared__ __align__(16) short ldsH[64 * 72];
    int tid = threadIdx.x, w = tid >> 6, l = tid & 63;
    int m = l & 15, ko = (l >> 4) * 8;
    int bx = blockIdx.x;
    int rt = blockIdx.y * 4 + w;
    size_t arow = (size_t)(rt * 16 + m) * DIN;
    bf16x8 aH0 = *(const bf16x8*)(Xh + arow + ko);
    bf16x8 aH1 = *(const bf16x8*)(Xh + arow + 32 + ko);
    int rg[4]; float T[4]; int rowcnt[4];
#pragma unroll
    for (int reg = 0; reg < 4; ++reg) {
        rg[reg] = rt * 16 + (l >> 4) * 4 + reg;
        T[reg] = tauf[rg[reg]] + EPS - sq[rg[reg]];
        rowcnt[reg] = 0;
    }
    int qs = l & 48;
    unsigned lmask = (1u << (l & 15)) - 1u;
    int srw = tid >> 3, scol8 = (tid & 7) * 8;

    for (int st = 0; st < 16; ++st) {
        int jbase = bx * 1024 + st * 64;
        __syncthreads();
        *(bf16x8*)&ldsH[srw * 72 + scol8] =
            *(const bf16x8*)(Xh + (size_t)(jbase + srw) * DIN + scol8);
        *(bf16x8*)&ldsH[(srw + 32) * 72 + scol8] =
            *(const bf16x8*)(Xh + (size_t)(jbase + srw + 32) * DIN + scol8);
        __syncthreads();
#pragma unroll
        for (int it = 0; it < 4; ++it) {
            int br = it * 16 + m;
            bf16x8 bH0 = *(const bf16x8*)&ldsH[br * 72 + ko];
            bf16x8 bH1 = *(const bf16x8*)&ldsH[br * 72 + 32 + ko];
            floatx4 acc = {0.f, 0.f, 0.f, 0.f};
            acc = __builtin_amdgcn_mfma_f32_16x16x32_bf16(aH0, bH0, acc, 0, 0, 0);
            acc = __builtin_amdgcn_mfma_f32_16x16x32_bf16(aH1, bH1, acc, 0, 0, 0);
            int jcol = jbase + it * 16 + m;
            float sqj = sq[jcol];
#pragma unroll
            for (int reg = 0; reg < 4; ++reg) {
                float tv = fmaf(-2.0f, acc[reg], sqj);   // dist - si
                bool pass = tv <= T[reg];
                u64 bal = __ballot(pass);
                unsigned m16 = (unsigned)((bal >> qs) & 0xFFFFull);
                if (pass) {
                    int slot = rowcnt[reg] + __popc(m16 & lmask);
                    if (slot < CAND_R)
                        cand[(size_t)rg[reg] * CAND_C + bx * CAND_R + slot] =
                            (unsigned short)jcol;
                }
                rowcnt[reg] += __popc(m16);
            }
        }
    }
    if ((l & 15) == 0) {
#pragma unroll
        for (int reg = 0; reg < 4; ++reg)
            cntpart[rg[reg] * NBX + bx] = (unsigned)min(rowcnt[reg], CAND_R);
    }
}

// K3: exact fp32 re-verify + top-16. One BLOCK per row, one thread per
// candidate. Row i is block-uniform -> SGPRs; candidate row read directly
// from global (L2-resident) with float4 loads; dot computed in the EXACT
// striped order of rounds 1-7 -> distances bit-identical to round 7.
__global__ __launch_bounds__(256) void k_exact(const float* __restrict__ x,
                                               const float* __restrict__ sq,
                                               const unsigned* __restrict__ cntpart,
                                               const unsigned short* __restrict__ cand,
                                               int* __restrict__ knn) {
    __shared__ unsigned short cj[CAND_C];    // 1.25 KB
    __shared__ u64 keys[CAND_C];             // 5 KB
    int t = threadIdx.x;
    int row = blockIdx.x;
    int base = 0;
#pragma unroll
    for (int b = 0; b < NBX; ++b) {          // compact candidate list
        int c = (int)cntpart[row * NBX + b]; // uniform -> scalar
        c = min(c, CAND_R);
        if (t < c) cj[base + t] = cand[(size_t)row * CAND_C + b * CAND_R + t];
        base += c;
    }
    __syncthreads();
    float sqi = sq[row];
    const float* xi = x + (size_t)row * DIN; // uniform -> s_load into SGPRs
    for (int c = t; c < base; c += 256) {
        int j = (int)cj[c];
        const float4* bj = (const float4*)(x + (size_t)j * DIN);
        float s0 = 0.f, s1 = 0.f, s2 = 0.f, s3 = 0.f;
#pragma unroll
        for (int q = 0; q < DIN / 4; ++q) {  // striped order == rounds 1-7
            float4 b = bj[q];
            s0 = fmaf(xi[4 * q + 0], b.x, s0);
            s1 = fmaf(xi[4 * q + 1], b.y, s1);
            s2 = fmaf(xi[4 * q + 2], b.z, s2);
            s3 = fmaf(xi[4 * q + 3], b.w, s3);
        }
        float d = (s0 + s1) + (s2 + s3);
        float dist = fmaf(-2.0f, d, sqi + sq[j]);
        keys[c] = ((u64)mono(dist) << 32) | (unsigned)j;
    }
    __syncthreads();
    if (t < 64) {                            // wave 0: 16-step min-extract
        u64 kk[CAND_C / 64];
#pragma unroll
        for (int u = 0; u < CAND_C / 64; ++u) {
            int idx = t + 64 * u;
            kk[u] = (idx < base) ? keys[idx] : 0xFFFFFFFFFFFFFFFFull;
        }
#pragma unroll
        for (int s = 0; s < KNN; ++s) {
            u64 mm = kk[0];
#pragma unroll
            for (int u = 1; u < CAND_C / 64; ++u) mm = (kk[u] < mm) ? kk[u] : mm;
#pragma unroll
            for (int off = 32; off >= 1; off >>= 1) {
                u64 o = __shfl_xor(mm, off, 64);
                mm = (o < mm) ? o : mm;
            }
            if (t == s) knn[row * KNN + s] = (int)(unsigned)(mm & 0xFFFFFFFFull);
#pragma unroll
            for (int u = 0; u < CAND_C / 64; ++u)
                if (kk[u] == mm) kk[u] = 0xFFFFFFFFFFFFFFFFull;
        }
    }
}

// K4: agg[i] = mean_j relu(U[i]+V[knn[i][j]]);  out = agg@W2 + b2.
__global__ __launch_bounds__(256) void k_aggout(const float* __restrict__ U,
                                                const float* __restrict__ V,
                                                const int* __restrict__ knn,
                                                const float* __restrict__ W2,
                                                const float* __restrict__ b2,
                                                float* __restrict__ out) {
    __shared__ float ag[2][DOUT];
    int t = threadIdx.x;
    int r = t >> 7;
    int o = t & 127;
    int i = blockIdx.x * 2 + r;
    float u = U[(size_t)i * DOUT + o];
    const int* nb = knn + i * KNN;
    float acc = 0.f;
#pragma unroll
    for (int q = 0; q < KNN; ++q) {
        int j = nb[q];
        float v = V[(size_t)j * DOUT + o];
        acc += fmaxf(u + v, 0.0f);
    }
    ag[r][o] = acc * (1.0f / KNN);
    __syncthreads();
    float a2 = 0.f;
#pragma unroll 4
    for (int kk = 0; kk < DOUT; ++kk)
        a2 = fmaf(ag[r][kk], W2[kk * DOUT + o], a2);
    out[(size_t)i * DOUT + o] = a2 + b2[o];
}

extern "C" void kernel_launch(void* const* d_in, const int* in_sizes, int n_in,
                              void* d_out, int out_size, void* d_ws, size_t ws_size,
                              hipStream_t stream) {
    const float* x  = (const float*)d_in[0];
    const float* W1 = (const float*)d_in[1];
    const float* b1 = (const float*)d_in[2];
    const float* W2 = (const float*)d_in[3];
    const float* b2 = (const float*)d_in[4];
    float* out = (float*)d_out;

    char* ws = (char*)d_ws;
    float*          sq      = (float*)(ws);                      // 32 KB
    float*          tauf    = (float*)(ws + 32768);              // 32 KB
    float*          U       = (float*)(ws + 65536);              // 4 MB
    float*          V       = (float*)(ws + 4259840);            // 4 MB
    int*            knn     = (int*)(ws + 8454144);              // 512 KB
    unsigned short* Xh      = (unsigned short*)(ws + 8978432);   // 1 MB
    unsigned*       cntpart = (unsigned*)(ws + 10027008);        // 256 KB
    char*           region  = ws + 10289152;                     // 16.8 MB shared:
    unsigned short* prekq   = (unsigned short*)region;           //  dead after k_tau
    unsigned short* cand    = (unsigned short*)region;           //  written after
    // total ws use ~27.1 MB

    k_pre<<<N / ROWS_PRE, 256, 0, stream>>>(x, W1, b1, sq, U, V, Xh);
    k_presample<<<dim3(4, 128), 256, 0, stream>>>(Xh, sq, prekq);
    k_tau<<<N / 4, 256, 0, stream>>>(prekq, tauf);
    k_main<<<dim3(NBX, 128), 256, 0, stream>>>(Xh, sq, tauf, cand, cntpart);
    k_exact<<<N, 256, 0, stream>>>(x, sq, cntpart, cand, knn);
    k_aggout<<<N / 2, 256, 0, stream>>>(U, V, knn, W2, b2, out);
}